// Round 17
// baseline (259.827 us; speedup 1.0000x reference)
//
#include <hip/hip_runtime.h>
#include <cstddef>
#include <cstdint>

namespace {

typedef __fp16 h2v __attribute__((ext_vector_type(2)));

constexpr int kB = 4096, kT = 1024, kI = 8, kH = 12, kA = 4;
constexpr int kTC  = 32;               // timesteps per staged chunk (r11-proven)
constexpr int kNCH = kT / kTC;         // 32 chunks
constexpr int kXRegU = 132;            // 128 payload uints + 4 pad per element region
constexpr int kBlkU  = 16 * kXRegU;    // 16 elements per block

constexpr float kL2E  = 1.442695041f;   // log2(e)
constexpr float kL2E2 = 2.885390082f;   // 2*log2(e)

template<int N>
__device__ __forceinline__ uint32_t ror16u(uint32_t v) {
    return (uint32_t)__builtin_amdgcn_mov_dpp((int)v, 0x120 + N, 0xF, 0xF, false);
}
__device__ __forceinline__ float ror16f1(float v) {
    return __int_as_float(__builtin_amdgcn_mov_dpp(__float_as_int(v), 0x121, 0xF, 0xF, false));
}
__device__ __forceinline__ uint32_t pkrtz(float lo, float hi) {
    return __builtin_bit_cast(uint32_t, __builtin_amdgcn_cvt_pkrtz(lo, hi));
}
__device__ __forceinline__ h2v uh(uint32_t u) { return __builtin_bit_cast(h2v, u); }
__device__ __forceinline__ float fd2(h2v w, h2v v, float acc) {
    return __builtin_amdgcn_fdot2(w, v, acc, false);
}
__device__ __forceinline__ float sigf(float s) {   // rcp(1+exp2(s)), scale pre-folded
    return __builtin_amdgcn_rcpf(1.0f + __builtin_amdgcn_exp2f(s));
}

__global__
__attribute__((amdgpu_flat_work_group_size(256, 256), amdgpu_waves_per_eu(1, 1)))
void lstm_fused_kernel(const float* __restrict__ x,
                       const float* __restrict__ W_ih,
                       const float* __restrict__ W_hh,
                       const float* __restrict__ b_ih,
                       const float* __restrict__ b_hh,
                       const float* __restrict__ W_fc,
                       const float* __restrict__ b_fc,
                       float* __restrict__ out) {
    __shared__ uint32_t xs[2][kBlkU];   // staged x (f16 pairs), double-buffered, wave-private

    const int tid = threadIdx.x;
    const int wv  = tid >> 6;           // wave in block
    const int l64 = tid & 63;           // lane in wave
    const int grp = l64 >> 4;           // 16-lane group == DPP row == element
    const int r   = l64 & 15;           // unit index within element (12..15 = FC rows)
    const int ei  = wv * 4 + grp;       // element index within block
    const int b   = blockIdx.x * 16 + ei;
    const bool isFC = (r >= kH);
    const int a   = isFC ? (r - kH) : 0;

    // DPP row_ror direction probe (r5..r11-proven)
    const int probe = __builtin_amdgcn_mov_dpp(r, 0x121, 0xF, 0xF, false);
    const int dir   = (probe - r) & 15;

    // ---- packed f16 weights, all 4 gates per lane; h-cols pre-rotated & paired ----
    h2v wp[4][8], xp[4][4];
    float bs[4];
    if (!isFC) {
#pragma unroll
        for (int g = 0; g < 4; ++g) {              // PyTorch gate order i,f,g,o
            const int row = g * kH + r;
            const float scl = (g == 2) ? -kL2E2 : -kL2E;   // tanh row gets 2*log2e
#pragma unroll
            for (int jj = 0; jj < 8; ++jj) {
                const int c0 = (r + dir * 2 * jj) & 15;
                const int c1 = (c0 + dir) & 15;
                const float u0 = (c0 < kH) ? W_hh[row * kH + c0] : 0.0f;
                const float u1 = (c1 < kH) ? W_hh[row * kH + c1] : 0.0f;
                wp[g][jj] = h2v{(__fp16)(scl * u0), (__fp16)(scl * u1)};
            }
#pragma unroll
            for (int i2 = 0; i2 < 4; ++i2)
                xp[g][i2] = h2v{(__fp16)(scl * W_ih[row * kI + 2 * i2]),
                                (__fp16)(scl * W_ih[row * kI + 2 * i2 + 1])};
            bs[g] = scl * (b_ih[row] + b_hh[row]);
        }
    } else {   // FC lane: gate0 = W_fc row (unscaled); gates 1-3 all-zero
#pragma unroll
        for (int jj = 0; jj < 8; ++jj) {
            const int c0 = (r + dir * 2 * jj) & 15;
            const int c1 = (c0 + dir) & 15;
            const float u0 = (c0 < kH) ? W_fc[a * kH + c0] : 0.0f;
            const float u1 = (c1 < kH) ? W_fc[a * kH + c1] : 0.0f;
            wp[0][jj] = h2v{(__fp16)u0, (__fp16)u1};
            wp[1][jj] = h2v{(__fp16)0.f, (__fp16)0.f};
            wp[2][jj] = wp[1][jj];
            wp[3][jj] = wp[1][jj];
        }
#pragma unroll
        for (int i2 = 0; i2 < 4; ++i2) {
            xp[0][i2] = h2v{(__fp16)0.f, (__fp16)0.f};
            xp[1][i2] = xp[0][i2]; xp[2][i2] = xp[0][i2]; xp[3][i2] = xp[0][i2];
        }
        bs[0] = b_fc[a]; bs[1] = 0.0f; bs[2] = 0.0f; bs[3] = 0.0f;
        // f=sig(0)=0.5, g=0, o=0.5 -> c,h stay EXACTLY 0 on FC lanes (r11-proven)
    }

    // ---- x staging: each group stages its own element (f32 global -> f16 LDS) ----
    const float* xg = x + (size_t)b * (kT * kI);
    const int reg = ei * kXRegU;

    float4 rv0, rv1, rv2, rv3;
    {   // prologue: chunk 0 -> buffer 0
        const float4* gp = (const float4*)xg;
        rv0 = gp[r]; rv1 = gp[16 + r]; rv2 = gp[32 + r]; rv3 = gp[48 + r];
        uint2 u;
        u.x = pkrtz(rv0.x, rv0.y); u.y = pkrtz(rv0.z, rv0.w);
        *(uint2*)&xs[0][reg + 2 * r] = u;
        u.x = pkrtz(rv1.x, rv1.y); u.y = pkrtz(rv1.z, rv1.w);
        *(uint2*)&xs[0][reg + 32 + 2 * r] = u;
        u.x = pkrtz(rv2.x, rv2.y); u.y = pkrtz(rv2.z, rv2.w);
        *(uint2*)&xs[0][reg + 64 + 2 * r] = u;
        u.x = pkrtz(rv3.x, rv3.y); u.y = pkrtz(rv3.z, rv3.w);
        *(uint2*)&xs[0][reg + 96 + 2 * r] = u;
    }
    asm volatile("s_waitcnt lgkmcnt(0)" ::: "memory");
    __builtin_amdgcn_sched_barrier(0);

    float h = 0.0f, c = 0.0f;
    uint32_t hrp[8];
#pragma unroll
    for (int k = 0; k < 8; ++k) hrp[k] = 0u;

    uint4 xr = *(const uint4*)&xs[0][reg];   // step 0: 8 f16

    float* op = out + (size_t)b * (kT * kA) + a;

    int cb = 0;
#pragma unroll 1
    for (int ch = 0; ch < kNCH; ++ch) {
        if (ch + 1 < kNCH) {   // issue next chunk's global loads early
            const float4* gp = (const float4*)(xg + (size_t)(ch + 1) * (kTC * kI));
            rv0 = gp[r]; rv1 = gp[16 + r]; rv2 = gp[32 + r]; rv3 = gp[48 + r];
        }
#pragma unroll
        for (int tt = 0; tt < kTC; ++tt) {
            // prefetch next step's x FIRST (max slack before use)
            uint4 xrn;
            if (tt + 1 < kTC) xrn = *(const uint4*)&xs[cb][reg + (tt + 1) * 4];
            // 4 gate dots, each as TWO 6-deep chains (x-terms head the chains so
            // they issue before the h-broadcast lands; h-critical path = 4 fdot2 + add)
            const h2v xv0 = uh(xr.x), xv1 = uh(xr.y), xv2 = uh(xr.z), xv3 = uh(xr.w);
            float a0 = fd2(xp[0][1], xv1, fd2(xp[0][0], xv0, bs[0]));
            float a1 = fd2(xp[1][1], xv1, fd2(xp[1][0], xv0, bs[1]));
            float a2 = fd2(xp[2][1], xv1, fd2(xp[2][0], xv0, bs[2]));
            float a3 = fd2(xp[3][1], xv1, fd2(xp[3][0], xv0, bs[3]));
            float q0 = fd2(xp[0][3], xv3, fd2(xp[0][2], xv2, 0.0f));
            float q1 = fd2(xp[1][3], xv3, fd2(xp[1][2], xv2, 0.0f));
            float q2 = fd2(xp[2][3], xv3, fd2(xp[2][2], xv2, 0.0f));
            float q3 = fd2(xp[3][3], xv3, fd2(xp[3][2], xv2, 0.0f));
#pragma unroll
            for (int jj = 0; jj < 4; ++jj) {
                const h2v hv = uh(hrp[jj]);
                a0 = fd2(wp[0][jj], hv, a0);
                a1 = fd2(wp[1][jj], hv, a1);
                a2 = fd2(wp[2][jj], hv, a2);
                a3 = fd2(wp[3][jj], hv, a3);
            }
#pragma unroll
            for (int jj = 4; jj < 8; ++jj) {
                const h2v hv = uh(hrp[jj]);
                q0 = fd2(wp[0][jj], hv, q0);
                q1 = fd2(wp[1][jj], hv, q1);
                q2 = fd2(wp[2][jj], hv, q2);
                q3 = fd2(wp[3][jj], hv, q3);
            }
            const float s0 = a0 + q0;
            const float s1 = a1 + q1;
            const float s2 = a2 + q2;
            const float s3 = a3 + q3;
            // FC lanes: s0 = wfc.h_{t-1} + b_fc = out[t-1] (delayed store)
            if ((ch | tt) != 0) { if (isFC) op[-kA] = s0; }
            // activations: paired reciprocals (4 rcp -> 2), scales pre-folded
            const float e0 = __builtin_amdgcn_exp2f(s0);
            const float e1 = __builtin_amdgcn_exp2f(s1);
            const float e2 = __builtin_amdgcn_exp2f(s2);
            const float e3 = __builtin_amdgcn_exp2f(s3);
            const float p0 = 1.0f + e0, p1 = 1.0f + e1;
            const float p2 = 1.0f + e2, p3 = 1.0f + e3;
            const float R01 = __builtin_amdgcn_rcpf(p0 * p1);
            const float R23 = __builtin_amdgcn_rcpf(p2 * p3);
            const float iv = p1 * R01;                      // 1/p0
            const float fv = p0 * R01;                      // 1/p1
            const float gv = fmaf(p3 + p3, R23, -1.0f);     // 2/p2 - 1
            const float ov = p2 * R23;                      // 1/p3
            // state update — fully in-lane, no cross-lane exchange
            c = fmaf(fv, c, iv * gv);
            const float tc = fmaf(2.0f, sigf(-kL2E2 * c), -1.0f);
            h = ov * tc;
            // packed h broadcast: Q = (h_r, h_{r+dir}); one DPP rotate = two h values
            const float hn1 = ror16f1(h);
            const uint32_t Q = pkrtz(h, hn1);
            hrp[0] = Q;
            hrp[1] = ror16u<2>(Q);
            hrp[2] = ror16u<4>(Q);
            hrp[3] = ror16u<6>(Q);
            hrp[4] = ror16u<8>(Q);
            hrp[5] = ror16u<10>(Q);
            hrp[6] = ror16u<12>(Q);
            hrp[7] = ror16u<14>(Q);
            if (tt + 1 < kTC) xr = xrn;
            op += kA;
        }
        if (ch + 1 < kNCH) {   // late LDS write of prefetched chunk + fence
            const int nb = cb ^ 1;
            uint2 u;
            u.x = pkrtz(rv0.x, rv0.y); u.y = pkrtz(rv0.z, rv0.w);
            *(uint2*)&xs[nb][reg + 2 * r] = u;
            u.x = pkrtz(rv1.x, rv1.y); u.y = pkrtz(rv1.z, rv1.w);
            *(uint2*)&xs[nb][reg + 32 + 2 * r] = u;
            u.x = pkrtz(rv2.x, rv2.y); u.y = pkrtz(rv2.z, rv2.w);
            *(uint2*)&xs[nb][reg + 64 + 2 * r] = u;
            u.x = pkrtz(rv3.x, rv3.y); u.y = pkrtz(rv3.z, rv3.w);
            *(uint2*)&xs[nb][reg + 96 + 2 * r] = u;
            asm volatile("s_waitcnt lgkmcnt(0)" ::: "memory");
            __builtin_amdgcn_sched_barrier(0);
            xr = *(const uint4*)&xs[nb][reg];
            cb = nb;
        }
    }

    {   // epilogue: out[T-1] = wfc . h_{T-1} + b_fc (full 8-pair h-dot)
        float s0 = bs[0];
#pragma unroll
        for (int jj = 0; jj < 8; ++jj)
            s0 = fd2(wp[0][jj], uh(hrp[jj]), s0);
        if (isFC) op[-kA] = s0;
    }
    if (!isFC) {   // hn, cn (fp32 master state), concatenated after out
        float* hn = out + (size_t)kB * kT * kA;
        hn[(size_t)b * kH + r] = h;
        hn[(size_t)kB * kH + (size_t)b * kH + r] = c;
    }
}

}  // namespace

extern "C" void kernel_launch(void* const* d_in, const int* in_sizes, int n_in,
                              void* d_out, int out_size, void* d_ws, size_t ws_size,
                              hipStream_t stream) {
    (void)in_sizes; (void)n_in; (void)d_ws; (void)ws_size; (void)out_size;
    const float* x    = (const float*)d_in[0];
    const float* W_ih = (const float*)d_in[1];
    const float* W_hh = (const float*)d_in[2];
    const float* b_ih = (const float*)d_in[3];
    const float* b_hh = (const float*)d_in[4];
    const float* W_fc = (const float*)d_in[5];
    const float* b_fc = (const float*)d_in[6];
    float* out = (float*)d_out;
    hipLaunchKernelGGL(lstm_fused_kernel, dim3(kB / 16), dim3(256), 0, stream,
                       x, W_ih, W_hh, b_ih, b_hh, W_fc, b_fc, out);
}

// Round 18
// 238.624 us; speedup vs baseline: 1.0889x; 1.0889x over previous
//
#include <hip/hip_runtime.h>
#include <cstddef>
#include <cstdint>

namespace {

typedef __fp16 h2v __attribute__((ext_vector_type(2)));

constexpr int kB = 4096, kT = 1024, kI = 8, kH = 12, kA = 4;
constexpr int kTC  = 32;               // timesteps per staged chunk (r11-proven)
constexpr int kNCH = kT / kTC;         // 32 chunks
constexpr int kXRegU = 132;            // 128 payload uints + 4 pad per element region
constexpr int kBlkU  = 16 * kXRegU;    // 16 elements per block

constexpr float kL2E  = 1.442695041f;   // log2(e)
constexpr float kL2E2 = 2.885390082f;   // 2*log2(e)

template<int N>
__device__ __forceinline__ uint32_t ror16u(uint32_t v) {
    return (uint32_t)__builtin_amdgcn_mov_dpp((int)v, 0x120 + N, 0xF, 0xF, false);
}
__device__ __forceinline__ float ror16f1(float v) {
    return __int_as_float(__builtin_amdgcn_mov_dpp(__float_as_int(v), 0x121, 0xF, 0xF, false));
}
__device__ __forceinline__ uint32_t pkrtz(float lo, float hi) {
    return __builtin_bit_cast(uint32_t, __builtin_amdgcn_cvt_pkrtz(lo, hi));
}
__device__ __forceinline__ h2v uh(uint32_t u) { return __builtin_bit_cast(h2v, u); }
__device__ __forceinline__ float fd2(h2v w, h2v v, float acc) {
    return __builtin_amdgcn_fdot2(w, v, acc, false);
}
__device__ __forceinline__ float sigf(float s) {   // rcp(1+exp2(s)), scale pre-folded
    return __builtin_amdgcn_rcpf(1.0f + __builtin_amdgcn_exp2f(s));
}

__global__
__attribute__((amdgpu_flat_work_group_size(256, 256), amdgpu_waves_per_eu(1, 1)))
void lstm_fused_kernel(const float* __restrict__ x,
                       const float* __restrict__ W_ih,
                       const float* __restrict__ W_hh,
                       const float* __restrict__ b_ih,
                       const float* __restrict__ b_hh,
                       const float* __restrict__ W_fc,
                       const float* __restrict__ b_fc,
                       float* __restrict__ out) {
    __shared__ uint32_t xs[2][kBlkU];   // staged x (f16 pairs), double-buffered, wave-private

    const int tid = threadIdx.x;
    const int wv  = tid >> 6;           // wave in block
    const int l64 = tid & 63;           // lane in wave
    const int grp = l64 >> 4;           // 16-lane group == DPP row == element
    const int r   = l64 & 15;           // unit index within element (12..15 = FC rows)
    const int ei  = wv * 4 + grp;       // element index within block
    const int b   = blockIdx.x * 16 + ei;
    const bool isFC = (r >= kH);
    const int a   = isFC ? (r - kH) : 0;

    // DPP row_ror direction probe (r5..r11-proven)
    const int probe = __builtin_amdgcn_mov_dpp(r, 0x121, 0xF, 0xF, false);
    const int dir   = (probe - r) & 15;

    // ---- packed f16 weights, all 4 gates per lane; h-cols pre-rotated & paired ----
    h2v wp[4][8], xp[4][4];
    float bs[4];
    if (!isFC) {
#pragma unroll
        for (int g = 0; g < 4; ++g) {              // PyTorch gate order i,f,g,o
            const int row = g * kH + r;
            const float scl = (g == 2) ? -kL2E2 : -kL2E;   // tanh row gets 2*log2e
#pragma unroll
            for (int jj = 0; jj < 8; ++jj) {
                const int c0 = (r + dir * 2 * jj) & 15;
                const int c1 = (c0 + dir) & 15;
                const float u0 = (c0 < kH) ? W_hh[row * kH + c0] : 0.0f;
                const float u1 = (c1 < kH) ? W_hh[row * kH + c1] : 0.0f;
                wp[g][jj] = h2v{(__fp16)(scl * u0), (__fp16)(scl * u1)};
            }
#pragma unroll
            for (int i2 = 0; i2 < 4; ++i2)
                xp[g][i2] = h2v{(__fp16)(scl * W_ih[row * kI + 2 * i2]),
                                (__fp16)(scl * W_ih[row * kI + 2 * i2 + 1])};
            bs[g] = scl * (b_ih[row] + b_hh[row]);
        }
    } else {   // FC lane: gate0 = W_fc row (unscaled); gates 1-3 all-zero
#pragma unroll
        for (int jj = 0; jj < 8; ++jj) {
            const int c0 = (r + dir * 2 * jj) & 15;
            const int c1 = (c0 + dir) & 15;
            const float u0 = (c0 < kH) ? W_fc[a * kH + c0] : 0.0f;
            const float u1 = (c1 < kH) ? W_fc[a * kH + c1] : 0.0f;
            wp[0][jj] = h2v{(__fp16)u0, (__fp16)u1};
            wp[1][jj] = h2v{(__fp16)0.f, (__fp16)0.f};
            wp[2][jj] = wp[1][jj];
            wp[3][jj] = wp[1][jj];
        }
#pragma unroll
        for (int i2 = 0; i2 < 4; ++i2) {
            xp[0][i2] = h2v{(__fp16)0.f, (__fp16)0.f};
            xp[1][i2] = xp[0][i2]; xp[2][i2] = xp[0][i2]; xp[3][i2] = xp[0][i2];
        }
        bs[0] = b_fc[a]; bs[1] = 0.0f; bs[2] = 0.0f; bs[3] = 0.0f;
        // f=sig(0)=0.5, g=0, o=0.5 -> c,h stay EXACTLY 0 on FC lanes (r11-proven)
    }

    // ---- x staging: each group stages its own element (f32 global -> f16 LDS) ----
    const float* xg = x + (size_t)b * (kT * kI);
    const int reg = ei * kXRegU;

    float4 rv0, rv1, rv2, rv3;
    {   // prologue: chunk 0 -> buffer 0
        const float4* gp = (const float4*)xg;
        rv0 = gp[r]; rv1 = gp[16 + r]; rv2 = gp[32 + r]; rv3 = gp[48 + r];
        uint2 u;
        u.x = pkrtz(rv0.x, rv0.y); u.y = pkrtz(rv0.z, rv0.w);
        *(uint2*)&xs[0][reg + 2 * r] = u;
        u.x = pkrtz(rv1.x, rv1.y); u.y = pkrtz(rv1.z, rv1.w);
        *(uint2*)&xs[0][reg + 32 + 2 * r] = u;
        u.x = pkrtz(rv2.x, rv2.y); u.y = pkrtz(rv2.z, rv2.w);
        *(uint2*)&xs[0][reg + 64 + 2 * r] = u;
        u.x = pkrtz(rv3.x, rv3.y); u.y = pkrtz(rv3.z, rv3.w);
        *(uint2*)&xs[0][reg + 96 + 2 * r] = u;
    }
    asm volatile("s_waitcnt lgkmcnt(0)" ::: "memory");
    __builtin_amdgcn_sched_barrier(0);

    float h = 0.0f, c = 0.0f;
    uint32_t hrp[8];
#pragma unroll
    for (int k = 0; k < 8; ++k) hrp[k] = 0u;

    uint4 xr = *(const uint4*)&xs[0][reg];   // step 0: 8 f16

    float* op = out + (size_t)b * (kT * kA) + a;

    int cb = 0;
#pragma unroll 1
    for (int ch = 0; ch < kNCH; ++ch) {
        if (ch + 1 < kNCH) {   // issue next chunk's global loads early
            const float4* gp = (const float4*)(xg + (size_t)(ch + 1) * (kTC * kI));
            rv0 = gp[r]; rv1 = gp[16 + r]; rv2 = gp[32 + r]; rv3 = gp[48 + r];
        }
#pragma unroll
        for (int tt = 0; tt < kTC; ++tt) {
            // prefetch next step's x FIRST (max slack before use)
            uint4 xrn;
            if (tt + 1 < kTC) xrn = *(const uint4*)&xs[cb][reg + (tt + 1) * 4];
            // 4 gate dots: 32 fdot2 over paired h + 16 over x (fp32 accum)
            float s0 = bs[0], s1 = bs[1], s2 = bs[2], s3 = bs[3];
#pragma unroll
            for (int jj = 0; jj < 8; ++jj) {
                const h2v hv = uh(hrp[jj]);
                s0 = fd2(wp[0][jj], hv, s0);
                s1 = fd2(wp[1][jj], hv, s1);
                s2 = fd2(wp[2][jj], hv, s2);
                s3 = fd2(wp[3][jj], hv, s3);
            }
            {
                const h2v xv0 = uh(xr.x), xv1 = uh(xr.y), xv2 = uh(xr.z), xv3 = uh(xr.w);
                s0 = fd2(xp[0][0], xv0, s0);
                s1 = fd2(xp[1][0], xv0, s1);
                s2 = fd2(xp[2][0], xv0, s2);
                s3 = fd2(xp[3][0], xv0, s3);
                s0 = fd2(xp[0][1], xv1, s0);
                s1 = fd2(xp[1][1], xv1, s1);
                s2 = fd2(xp[2][1], xv1, s2);
                s3 = fd2(xp[3][1], xv1, s3);
                s0 = fd2(xp[0][2], xv2, s0);
                s1 = fd2(xp[1][2], xv2, s1);
                s2 = fd2(xp[2][2], xv2, s2);
                s3 = fd2(xp[3][2], xv2, s3);
                s0 = fd2(xp[0][3], xv3, s0);
                s1 = fd2(xp[1][3], xv3, s1);
                s2 = fd2(xp[2][3], xv3, s2);
                s3 = fd2(xp[3][3], xv3, s3);
            }
            // FC lanes: s0 = wfc.h_{t-1} + b_fc = out[t-1] (delayed store)
            if ((ch | tt) != 0) { if (isFC) op[-kA] = s0; }
            // activations: paired reciprocals (4 rcp -> 2), scales pre-folded
            const float e0 = __builtin_amdgcn_exp2f(s0);
            const float e1 = __builtin_amdgcn_exp2f(s1);
            const float e2 = __builtin_amdgcn_exp2f(s2);
            const float e3 = __builtin_amdgcn_exp2f(s3);
            const float p0 = 1.0f + e0, p1 = 1.0f + e1;
            const float p2 = 1.0f + e2, p3 = 1.0f + e3;
            const float R01 = __builtin_amdgcn_rcpf(p0 * p1);
            const float R23 = __builtin_amdgcn_rcpf(p2 * p3);
            const float iv = p1 * R01;                      // 1/p0
            const float fv = p0 * R01;                      // 1/p1
            const float gv = fmaf(p3 + p3, R23, -1.0f);     // 2/p2 - 1
            const float ov = p2 * R23;                      // 1/p3
            // state update — fully in-lane, no cross-lane exchange
            c = fmaf(fv, c, iv * gv);
            const float tc = fmaf(2.0f, sigf(-kL2E2 * c), -1.0f);
            h = ov * tc;
            // packed h broadcast: Q = (h_r, h_{r+dir}); one DPP rotate = two h values
            const float hn1 = ror16f1(h);
            const uint32_t Q = pkrtz(h, hn1);
            hrp[0] = Q;
            hrp[1] = ror16u<2>(Q);
            hrp[2] = ror16u<4>(Q);
            hrp[3] = ror16u<6>(Q);
            hrp[4] = ror16u<8>(Q);
            hrp[5] = ror16u<10>(Q);
            hrp[6] = ror16u<12>(Q);
            hrp[7] = ror16u<14>(Q);
            if (tt + 1 < kTC) xr = xrn;
            op += kA;
        }
        if (ch + 1 < kNCH) {   // late LDS write of prefetched chunk + fence
            const int nb = cb ^ 1;
            uint2 u;
            u.x = pkrtz(rv0.x, rv0.y); u.y = pkrtz(rv0.z, rv0.w);
            *(uint2*)&xs[nb][reg + 2 * r] = u;
            u.x = pkrtz(rv1.x, rv1.y); u.y = pkrtz(rv1.z, rv1.w);
            *(uint2*)&xs[nb][reg + 32 + 2 * r] = u;
            u.x = pkrtz(rv2.x, rv2.y); u.y = pkrtz(rv2.z, rv2.w);
            *(uint2*)&xs[nb][reg + 64 + 2 * r] = u;
            u.x = pkrtz(rv3.x, rv3.y); u.y = pkrtz(rv3.z, rv3.w);
            *(uint2*)&xs[nb][reg + 96 + 2 * r] = u;
            asm volatile("s_waitcnt lgkmcnt(0)" ::: "memory");
            __builtin_amdgcn_sched_barrier(0);
            xr = *(const uint4*)&xs[nb][reg];
            cb = nb;
        }
    }

    {   // epilogue: out[T-1] = wfc . h_{T-1} + b_fc (full 8-pair h-dot)
        float s0 = bs[0];
#pragma unroll
        for (int jj = 0; jj < 8; ++jj)
            s0 = fd2(wp[0][jj], uh(hrp[jj]), s0);
        if (isFC) op[-kA] = s0;
    }
    if (!isFC) {   // hn, cn (fp32 master state), concatenated after out
        float* hn = out + (size_t)kB * kT * kA;
        hn[(size_t)b * kH + r] = h;
        hn[(size_t)kB * kH + (size_t)b * kH + r] = c;
    }
}

}  // namespace

extern "C" void kernel_launch(void* const* d_in, const int* in_sizes, int n_in,
                              void* d_out, int out_size, void* d_ws, size_t ws_size,
                              hipStream_t stream) {
    (void)in_sizes; (void)n_in; (void)d_ws; (void)ws_size; (void)out_size;
    const float* x    = (const float*)d_in[0];
    const float* W_ih = (const float*)d_in[1];
    const float* W_hh = (const float*)d_in[2];
    const float* b_ih = (const float*)d_in[3];
    const float* b_hh = (const float*)d_in[4];
    const float* W_fc = (const float*)d_in[5];
    const float* b_fc = (const float*)d_in[6];
    float* out = (float*)d_out;
    hipLaunchKernelGGL(lstm_fused_kernel, dim3(kB / 16), dim3(256), 0, stream,
                       x, W_ih, W_hh, b_ih, b_hh, W_fc, b_fc, out);
}